// Round 1
// baseline (1157.822 us; speedup 1.0000x reference)
//
#include <hip/hip_runtime.h>

#define B_   8
#define S_   2048
#define H_   768
#define K_   128
#define C_   256
#define SH_  2052              // S + 4 halo rows (2 each side)
#define MTOK (B_*S_)           // 16384 tokens

typedef __attribute__((ext_vector_type(8))) short short8;
typedef __attribute__((ext_vector_type(4))) float f32x4;

__device__ __forceinline__ ushort f2b(float f) {
    union { float f; unsigned u; } v; v.f = f;
    unsigned r = v.u + 0x7fffu + ((v.u >> 16) & 1u);   // RNE
    return (ushort)(r >> 16);
}
__device__ __forceinline__ float b2f(ushort u) {
    union { unsigned u; float f; } v; v.u = ((unsigned)u) << 16;
    return v.f;
}
__device__ __forceinline__ float fast_tanh(float x) {
    float e = __expf(2.f * x);
    return 1.f - 2.f / (e + 1.f);
}

// ---------------- small prep kernels ----------------

__global__ void k_maxlen(const float* __restrict__ mask, int* Lp) {
    __shared__ float sh[256];
    float mx = 0.f;
    for (int b = 0; b < B_; ++b) {
        float s = 0.f;
        for (int i = threadIdx.x; i < S_; i += 256) s += mask[b * S_ + i];
        sh[threadIdx.x] = s;
        __syncthreads();
        for (int off = 128; off; off >>= 1) {
            if (threadIdx.x < off) sh[threadIdx.x] += sh[threadIdx.x + off];
            __syncthreads();
        }
        if (threadIdx.x == 0) mx = fmaxf(mx, sh[0]);
        __syncthreads();
    }
    if (threadIdx.x == 0) *Lp = (int)mx;
}

// build halo'd bf16 copy of representation: Xh[b][s'][h], s' in [0,SH), rows 0,1,S+2,S+3 zero
__global__ void k_build_xh(const float* __restrict__ rep, ushort* __restrict__ xh) {
    int i = blockIdx.x * blockDim.x + threadIdx.x;
    int stride = gridDim.x * blockDim.x;
    const int n = B_ * SH_ * H_;
    for (; i < n; i += stride) {
        int h = i % H_;
        int rs = i / H_;
        int s = rs % SH_;
        int b = rs / SH_;
        float v = 0.f;
        if (s >= 2 && s < S_ + 2) v = rep[((size_t)b * S_ + (s - 2)) * H_ + h];
        xh[i] = f2b(v);
    }
}

// plain f32 -> bf16
__global__ void k_cvt(const float* __restrict__ src, ushort* __restrict__ dst, int n) {
    int i = blockIdx.x * blockDim.x + threadIdx.x;
    int stride = gridDim.x * blockDim.x;
    for (; i < n; i += stride) dst[i] = f2b(src[i]);
}

// conv weight [KH][C] f32  ->  [C][KH] bf16 (B^T layout)
__global__ void k_cvt_convw(const float* __restrict__ src, ushort* __restrict__ dst, int KH) {
    int i = blockIdx.x * blockDim.x + threadIdx.x;
    int stride = gridDim.x * blockDim.x;
    const int n = KH * C_;
    for (; i < n; i += stride) {
        int c = i / KH;
        int r = i - c * KH;
        dst[i] = f2b(src[r * C_ + c]);
    }
}

// ---------------- GEMM (direct-fragment MFMA, B^T weights) ----------------
// out[m,n] = act( sum_k A[m,k] * Wt[n,k] )
// CONV mode: A is halo'd [B][SH][H] bf16, K dim = ksize*768, tap t = kk/768

struct GemmP {
    const ushort* A;    // bf16
    const ushort* Wt;   // bf16 [N][Ktot]
    int Ktot;
    int lda;            // A row stride (elements)
    int ksize;          // 0 = linear, else 1/3/5 conv
    ushort* outB;       // bf16 out (nullable)
    int ldoB;
    int coloffB;
    int outB_halo;      // row' = r + 4*b + 2
    float* outF;        // f32 out (nullable)
    int ldoF;
    int act;            // 1 = tanh
};

__global__ __launch_bounds__(256) void gemm_bt(GemmP p) {
    const int wid  = threadIdx.x >> 6;
    const int lane = threadIdx.x & 63;
    const int l15  = lane & 15;
    const int lk   = lane >> 4;                 // 0..3
    const int m_base = blockIdx.x * 128 + wid * 32;
    const int c0 = blockIdx.y * 64;
    const int bb = (blockIdx.x * 128) >> 11;    // batch of this M-tile (tiles never straddle)

    f32x4 acc[2][4] = {};
    const int hoff = p.ksize ? (2 - p.ksize / 2) : 0;
    const int nk = p.Ktot >> 5;

    for (int kt = 0; kt < nk; ++kt) {
        const int kk = kt << 5;
        int t = 0, h0 = kk;
        if (p.ksize) { t = kk / 768; h0 = kk - t * 768; }
        const int r0 = m_base + l15;
        const int arow = p.ksize ? (r0 + 4 * bb + hoff + t) : r0;
        const short8 a0 = *(const short8*)(p.A + (size_t)arow        * p.lda + h0 + 8 * lk);
        const short8 a1 = *(const short8*)(p.A + (size_t)(arow + 16) * p.lda + h0 + 8 * lk);
#pragma unroll
        for (int j = 0; j < 4; ++j) {
            const short8 bfr = *(const short8*)(p.Wt + (size_t)(c0 + j * 16 + l15) * p.Ktot + kk + 8 * lk);
            acc[0][j] = __builtin_amdgcn_mfma_f32_16x16x32_bf16(a0, bfr, acc[0][j], 0, 0, 0);
            acc[1][j] = __builtin_amdgcn_mfma_f32_16x16x32_bf16(a1, bfr, acc[1][j], 0, 0, 0);
        }
    }

#pragma unroll
    for (int i = 0; i < 2; ++i) {
#pragma unroll
        for (int j = 0; j < 4; ++j) {
#pragma unroll
            for (int jj = 0; jj < 4; ++jj) {
                const int r = m_base + i * 16 + 4 * lk + jj;
                const int n = c0 + j * 16 + l15;
                float v = acc[i][j][jj];
                if (p.act) v = fast_tanh(v);
                if (p.outF) p.outF[(size_t)r * p.ldoF + n] = v;
                if (p.outB) {
                    const int rr = p.outB_halo ? (r + 4 * bb + 2) : r;
                    p.outB[(size_t)rr * p.ldoB + p.coloffB + n] = f2b(v);
                }
            }
        }
    }
}

// ---------------- LayerNorm(conv_out + residual) -> bf16 ----------------

__global__ __launch_bounds__(256) void k_ln(const ushort* __restrict__ conv,
                                            const float* __restrict__ rep,
                                            const float* __restrict__ gw,
                                            const float* __restrict__ bw,
                                            ushort* __restrict__ out) {
    const int row = blockIdx.x;
    const ushort* cp = conv + (size_t)row * H_;
    const float*  rp = rep  + (size_t)row * H_;
    const int tid = threadIdx.x;
    float v[3];
#pragma unroll
    for (int q = 0; q < 3; ++q) { int h = tid + q * 256; v[q] = b2f(cp[h]) + rp[h]; }
    float s1 = v[0] + v[1] + v[2];
    float s2 = v[0] * v[0] + v[1] * v[1] + v[2] * v[2];
#pragma unroll
    for (int off = 32; off; off >>= 1) { s1 += __shfl_xor(s1, off); s2 += __shfl_xor(s2, off); }
    __shared__ float sh[8];
    const int wid = tid >> 6, lane = tid & 63;
    if (lane == 0) { sh[wid] = s1; sh[4 + wid] = s2; }
    __syncthreads();
    s1 = sh[0] + sh[1] + sh[2] + sh[3];
    s2 = sh[4] + sh[5] + sh[6] + sh[7];
    const float mu  = s1 * (1.f / H_);
    const float var = s2 * (1.f / H_) - mu * mu;
    const float rs  = rsqrtf(var + 1e-5f);
    ushort* op = out + (size_t)row * H_;
#pragma unroll
    for (int q = 0; q < 3; ++q) {
        int h = tid + q * 256;
        op[h] = f2b((v[q] - mu) * rs * gw[h] + bw[h]);
    }
}

// ---------------- row-normalize location -> bf16 ----------------

__global__ __launch_bounds__(256) void k_normed(const float* __restrict__ loc, ushort* __restrict__ out) {
    const int wid = threadIdx.x >> 6, lane = threadIdx.x & 63;
    const int row = blockIdx.x * 4 + wid;
    const float* lp = loc + (size_t)row * K_;
    const float x0 = lp[lane], x1 = lp[lane + 64];
    float ss = x0 * x0 + x1 * x1;
#pragma unroll
    for (int off = 32; off; off >>= 1) ss += __shfl_xor(ss, off);
    const float sc = 1.f / fmaxf(sqrtf(ss), 1e-8f);
    ushort* op = out + (size_t)row * K_;
    op[lane] = f2b(x0 * sc);
    op[lane + 64] = f2b(x1 * sc);
}

// ---------------- banded cosine-sim: dis[b,i,j] ----------------

__global__ __launch_bounds__(256) void k_sim(const ushort* __restrict__ normed,
                                             const int* __restrict__ Lp,
                                             float* __restrict__ dis) {
    const int wid = threadIdx.x >> 6, lane = threadIdx.x & 63;
    const int l15 = lane & 15, lk = lane >> 4;
    const int b  = blockIdx.z;
    const int i0 = blockIdx.x * 64 + wid * 16;
    const int j0 = blockIdx.y * 64;
    const ushort* nb = normed + (size_t)b * S_ * K_;
    f32x4 acc[4] = {};
#pragma unroll
    for (int kt = 0; kt < 4; ++kt) {
        const int kk = kt * 32;
        const short8 a = *(const short8*)(nb + (size_t)(i0 + l15) * K_ + kk + 8 * lk);
#pragma unroll
        for (int j = 0; j < 4; ++j) {
            const short8 bfr = *(const short8*)(nb + (size_t)(j0 + j * 16 + l15) * K_ + kk + 8 * lk);
            acc[j] = __builtin_amdgcn_mfma_f32_16x16x32_bf16(a, bfr, acc[j], 0, 0, 0);
        }
    }
    const int L = *Lp;
    float* dp = dis + (size_t)b * S_ * S_;
#pragma unroll
    for (int j = 0; j < 4; ++j) {
#pragma unroll
        for (int jj = 0; jj < 4; ++jj) {
            const int i  = i0 + 4 * lk + jj;
            const int jc = j0 + j * 16 + l15;
            const int d  = jc - i;
            dp[(size_t)i * S_ + jc] = (d >= 1 && d <= L) ? acc[j][jj] : 0.f;
        }
    }
}

// ---------------- tags[b,i,j] = band * mask_i * mask_j ----------------

__global__ void k_tags(const float* __restrict__ mask, const int* __restrict__ Lp,
                       float* __restrict__ tags) {
    const int L = *Lp;
    size_t i4 = (size_t)blockIdx.x * blockDim.x + threadIdx.x;
    const size_t stride = (size_t)gridDim.x * blockDim.x;
    const size_t n4 = (size_t)B_ * S_ * S_ / 4;
    for (; i4 < n4; i4 += stride) {
        const size_t idx = i4 * 4;
        const int b = (int)(idx / ((size_t)S_ * S_));
        const int rem = (int)(idx % ((size_t)S_ * S_));
        const int i = rem / S_;
        const int j = rem % S_;
        const float mi = mask[b * S_ + i];
        const float4 mj = *(const float4*)(mask + b * S_ + j);
        float4 o;
        int d0 = j - i;
        o.x = (d0 + 0 >= 1 && d0 + 0 <= L) ? mi * mj.x : 0.f;
        o.y = (d0 + 1 >= 1 && d0 + 1 <= L) ? mi * mj.y : 0.f;
        o.z = (d0 + 2 >= 1 && d0 + 2 <= L) ? mi * mj.z : 0.f;
        o.w = (d0 + 3 >= 1 && d0 + 3 <= L) ? mi * mj.w : 0.f;
        *(float4*)(tags + idx) = o;
    }
}

// ---------------- host launch ----------------

extern "C" void kernel_launch(void* const* d_in, const int* in_sizes, int n_in,
                              void* d_out, int out_size, void* d_ws, size_t ws_size,
                              hipStream_t stream) {
    const float* rep  = (const float*)d_in[0];
    const float* mask = (const float*)d_in[1];
    const float* ew1  = (const float*)d_in[2];
    const float* ew3  = (const float*)d_in[3];
    const float* ew5  = (const float*)d_in[4];
    const float* lng  = (const float*)d_in[5];
    const float* lnb  = (const float*)d_in[6];
    const float* elin = (const float*)d_in[7];
    const float* etr  = (const float*)d_in[8];
    const float* dtr  = (const float*)d_in[9];
    const float* dw1  = (const float*)d_in[10];
    const float* dw3  = (const float*)d_in[11];
    const float* dw5  = (const float*)d_in[12];
    const float* dlin = (const float*)d_in[13];
    const float* olin = (const float*)d_in[14];

    float* out_loc = (float*)d_out;                               // [8,2048,128]
    float* out_dis = out_loc + (size_t)B_ * S_ * K_;              // [8,2048,2048]
    float* out_tag = out_dis + (size_t)B_ * S_ * S_;              // [8,2048,2048]
    float* out_dec = out_tag + (size_t)B_ * S_ * S_;              // [8,2048,768]

    char* ws = (char*)d_ws;
    size_t off = 0;
    auto alloc = [&](size_t bytes) -> char* {
        char* p = ws + off;
        off += (bytes + 255) & ~(size_t)255;
        return p;
    };
    int*    Lp    = (int*)alloc(256);
    ushort* Xh    = (ushort*)alloc((size_t)B_ * SH_ * H_ * 2);  // also reused as halo'd d0
    ushort* wte1  = (ushort*)alloc((size_t)C_ * 768 * 2);
    ushort* wte3  = (ushort*)alloc((size_t)C_ * 2304 * 2);
    ushort* wte5  = (ushort*)alloc((size_t)C_ * 3840 * 2);
    ushort* wtd1  = (ushort*)alloc((size_t)C_ * 768 * 2);
    ushort* wtd3  = (ushort*)alloc((size_t)C_ * 2304 * 2);
    ushort* wtd5  = (ushort*)alloc((size_t)C_ * 3840 * 2);
    ushort* welin = (ushort*)alloc((size_t)H_ * H_ * 2);
    ushort* wetr  = (ushort*)alloc((size_t)K_ * H_ * 2);
    ushort* wdtr  = (ushort*)alloc((size_t)H_ * K_ * 2);
    ushort* wdlin = (ushort*)alloc((size_t)H_ * H_ * 2);
    ushort* wolin = (ushort*)alloc((size_t)H_ * H_ * 2);
    ushort* bufB  = (ushort*)alloc((size_t)MTOK * H_ * 2);      // conv_enc_out, then d1
    ushort* bufC  = (ushort*)alloc((size_t)MTOK * H_ * 2);      // h_ln, then d2
    ushort* bufD  = (ushort*)alloc((size_t)MTOK * H_ * 2);      // h2
    ushort* bufL  = (ushort*)alloc((size_t)MTOK * K_ * 2);      // location bf16
    ushort* bufN  = (ushort*)alloc((size_t)MTOK * K_ * 2);      // normed bf16
    if (ws_size < off) return;  // insufficient workspace

    // 1. max_act_len
    k_maxlen<<<1, 256, 0, stream>>>(mask, Lp);
    // 2. halo'd bf16 input
    k_build_xh<<<4096, 256, 0, stream>>>(rep, Xh);
    // 3. weight conversions
    auto cvt = [&](const float* s, ushort* d, int n) {
        int blocks = (n + 255) / 256; if (blocks > 4096) blocks = 4096;
        k_cvt<<<blocks, 256, 0, stream>>>(s, d, n);
    };
    auto cvtw = [&](const float* s, ushort* d, int KH) {
        int n = KH * C_;
        int blocks = (n + 255) / 256; if (blocks > 4096) blocks = 4096;
        k_cvt_convw<<<blocks, 256, 0, stream>>>(s, d, KH);
    };
    cvtw(ew1, wte1, 768);  cvtw(ew3, wte3, 2304);  cvtw(ew5, wte5, 3840);
    cvtw(dw1, wtd1, 768);  cvtw(dw3, wtd3, 2304);  cvtw(dw5, wtd5, 3840);
    cvt(elin, welin, H_ * H_);
    cvt(etr,  wetr,  K_ * H_);
    cvt(dtr,  wdtr,  H_ * K_);
    cvt(dlin, wdlin, H_ * H_);
    cvt(olin, wolin, H_ * H_);

    auto gemm = [&](GemmP p, int N) {
        dim3 grid(MTOK / 128, N / 64);
        gemm_bt<<<grid, 256, 0, stream>>>(p);
    };

    // 4. encoder convs -> bufB (cols 0/256/512)
    {
        GemmP p{}; p.A = Xh; p.lda = H_; p.outB = bufB; p.ldoB = H_;
        p.Wt = wte1; p.Ktot = 768;  p.ksize = 1; p.coloffB = 0;   gemm(p, C_);
        p.Wt = wte3; p.Ktot = 2304; p.ksize = 3; p.coloffB = 256; gemm(p, C_);
        p.Wt = wte5; p.Ktot = 3840; p.ksize = 5; p.coloffB = 512; gemm(p, C_);
    }
    // 5. LN(conv + rep) -> bufC
    k_ln<<<MTOK, 256, 0, stream>>>(bufB, rep, lng, lnb, bufC);
    // 6. h2 = tanh(h_ln @ enc_lin^T) -> bufD
    {
        GemmP p{}; p.A = bufC; p.lda = H_; p.Wt = welin; p.Ktot = H_;
        p.outB = bufD; p.ldoB = H_; p.act = 1; gemm(p, H_);
    }
    // 7. location = h2 @ enc_tr^T -> out_loc (f32) + bufL (bf16)
    {
        GemmP p{}; p.A = bufD; p.lda = H_; p.Wt = wetr; p.Ktot = H_;
        p.outF = out_loc; p.ldoF = K_; p.outB = bufL; p.ldoB = K_; gemm(p, K_);
    }
    // 8. normed -> bufN
    k_normed<<<MTOK / 4, 256, 0, stream>>>(out_loc, bufN);
    // 9. d0 = location @ dec_tr^T -> Xh interior (halo'd rows, halos stay zero)
    {
        GemmP p{}; p.A = bufL; p.lda = K_; p.Wt = wdtr; p.Ktot = K_;
        p.outB = Xh; p.ldoB = H_; p.outB_halo = 1; gemm(p, H_);
    }
    // 10. decoder convs -> bufB (d1)
    {
        GemmP p{}; p.A = Xh; p.lda = H_; p.outB = bufB; p.ldoB = H_;
        p.Wt = wtd1; p.Ktot = 768;  p.ksize = 1; p.coloffB = 0;   gemm(p, C_);
        p.Wt = wtd3; p.Ktot = 2304; p.ksize = 3; p.coloffB = 256; gemm(p, C_);
        p.Wt = wtd5; p.Ktot = 3840; p.ksize = 5; p.coloffB = 512; gemm(p, C_);
    }
    // 11. d2 = tanh(d1 @ dec_lin^T) -> bufC
    {
        GemmP p{}; p.A = bufB; p.lda = H_; p.Wt = wdlin; p.Ktot = H_;
        p.outB = bufC; p.ldoB = H_; p.act = 1; gemm(p, H_);
    }
    // 12. decode_out = d2 @ out_lin^T -> out_dec (f32)
    {
        GemmP p{}; p.A = bufC; p.lda = H_; p.Wt = wolin; p.Ktot = H_;
        p.outF = out_dec; p.ldoF = H_; gemm(p, H_);
    }
    // 13. banded cosine sim -> out_dis
    k_sim<<<dim3(S_ / 64, S_ / 64, B_), 256, 0, stream>>>(bufN, Lp, out_dis);
    // 14. tags -> out_tag
    k_tags<<<4096, 256, 0, stream>>>(mask, Lp, out_tag);
}

// Round 2
// 537.888 us; speedup vs baseline: 2.1525x; 2.1525x over previous
//
#include <hip/hip_runtime.h>

#define B_   8
#define S_   2048
#define H_   768
#define K_   128
#define C_   256
#define SH_  2052              // S + 4 halo rows (2 each side)
#define MTOK (B_*S_)           // 16384 tokens

typedef __attribute__((ext_vector_type(8))) short short8;
typedef __attribute__((ext_vector_type(4))) float f32x4;

typedef __attribute__((address_space(1))) const void gvoid;
typedef __attribute__((address_space(3))) void lvoid;

__device__ __forceinline__ void gload16(const void* g, void* l) {
    __builtin_amdgcn_global_load_lds((gvoid*)g, (lvoid*)l, 16, 0, 0);
}

__device__ __forceinline__ ushort f2b(float f) {
    union { float f; unsigned u; } v; v.f = f;
    unsigned r = v.u + 0x7fffu + ((v.u >> 16) & 1u);   // RNE
    return (ushort)(r >> 16);
}
__device__ __forceinline__ float b2f(ushort u) {
    union { unsigned u; float f; } v; v.u = ((unsigned)u) << 16;
    return v.f;
}
__device__ __forceinline__ float fast_tanh(float x) {
    float e = __expf(2.f * x);
    return 1.f - 2.f / (e + 1.f);
}

// ---------------- small prep kernels ----------------

__global__ void k_maxlen(const float* __restrict__ mask, int* Lp) {
    __shared__ float sh[256];
    float mx = 0.f;
    for (int b = 0; b < B_; ++b) {
        float s = 0.f;
        for (int i = threadIdx.x; i < S_; i += 256) s += mask[b * S_ + i];
        sh[threadIdx.x] = s;
        __syncthreads();
        for (int off = 128; off; off >>= 1) {
            if (threadIdx.x < off) sh[threadIdx.x] += sh[threadIdx.x + off];
            __syncthreads();
        }
        if (threadIdx.x == 0) mx = fmaxf(mx, sh[0]);
        __syncthreads();
    }
    if (threadIdx.x == 0) *Lp = (int)mx;
}

// build halo'd bf16 copy of representation (vectorized x4)
__global__ void k_build_xh(const float* __restrict__ rep, ushort* __restrict__ xh) {
    int i = blockIdx.x * blockDim.x + threadIdx.x;
    const int stride = gridDim.x * blockDim.x;
    const int n4 = B_ * SH_ * H_ / 4;
    for (; i < n4; i += stride) {
        const int idx = i * 4;
        const int h = idx % H_;
        const int rs = idx / H_;
        const int s = rs % SH_;
        const int b = rs / SH_;
        ushort4 o; o.x = 0; o.y = 0; o.z = 0; o.w = 0;
        if (s >= 2 && s < S_ + 2) {
            const float4 v = *(const float4*)(rep + ((size_t)b * S_ + (s - 2)) * H_ + h);
            o.x = f2b(v.x); o.y = f2b(v.y); o.z = f2b(v.z); o.w = f2b(v.w);
        }
        *(ushort4*)(xh + idx) = o;
    }
}

// fused weight conversions: 11 entries in one launch
struct CvtE { const float* src; ushort* dst; int n; int kh; };  // kh=0: copy, else [KH][C]->[C][KH]
struct CvtAll { CvtE e[11]; };

__global__ void k_cvt_all(CvtAll a) {
    const CvtE e = a.e[blockIdx.y];
    int i = blockIdx.x * blockDim.x + threadIdx.x;
    const int stride = gridDim.x * blockDim.x;
    for (; i < e.n; i += stride) {
        if (e.kh) {
            const int c = i / e.kh;
            const int r = i - c * e.kh;
            e.dst[i] = f2b(e.src[r * C_ + c]);
        } else {
            e.dst[i] = f2b(e.src[i]);
        }
    }
}

// ---------------- LDS-staged MFMA GEMM (m97 structure, B^T weights) ----------------
// out[m,n] = act( sum_k A[m,k] * Wt[n,k] )

struct GemmP {
    const ushort* A;    // bf16 [M][lda]
    const ushort* Wt;   // bf16 [N][Ktot]
    int Ktot;
    int lda;
    ushort* outB;       // bf16 out (nullable)
    int ldoB;
    int outB_halo;      // row' = r + 4*(r>>11) + 2
    float* outF;        // f32 out (nullable)
    int ldoF;
    int act;            // 1 = tanh
};

template<int BM, int BN>
__global__ __launch_bounds__(256) void gemm_lds(GemmP p) {
    constexpr int MF = BM / 32;        // 16-row frags per wave
    constexpr int NF = BN / 32;        // 16-col frags per wave
    __shared__ __align__(16) ushort As[BM * 64];
    __shared__ __align__(16) ushort Bs[BN * 64];
    const int tid = threadIdx.x;
    const int w = tid >> 6, lane = tid & 63;
    const int l15 = lane & 15, lk = lane >> 4;
    const int m_base = blockIdx.x * BM;
    const int n_base = blockIdx.y * BN;
    const int wr = w >> 1, wc = w & 1;
    f32x4 acc[MF][NF] = {};
    const int srow = lane >> 3;          // 0..7
    const int scol = (lane & 7) * 8;     // elems
    const int nk = p.Ktot >> 6;

    for (int kt = 0; kt < nk; ++kt) {
        const int kk = kt << 6;
#pragma unroll
        for (int q = 0; q < BM / 32; ++q) {
            const int r = w * (BM / 4) + q * 8;
            gload16(p.A + (size_t)(m_base + r + srow) * p.lda + kk + scol, As + r * 64);
        }
#pragma unroll
        for (int q = 0; q < BN / 32; ++q) {
            const int r = w * (BN / 4) + q * 8;
            gload16(p.Wt + (size_t)(n_base + r + srow) * p.Ktot + kk + scol, Bs + r * 64);
        }
        __syncthreads();
#pragma unroll
        for (int ks = 0; ks < 2; ++ks) {
            short8 af[MF], bf[NF];
#pragma unroll
            for (int i = 0; i < MF; ++i)
                af[i] = *(const short8*)(As + (wr * (BM / 2) + i * 16 + l15) * 64 + ks * 32 + 8 * lk);
#pragma unroll
            for (int j = 0; j < NF; ++j)
                bf[j] = *(const short8*)(Bs + (wc * (BN / 2) + j * 16 + l15) * 64 + ks * 32 + 8 * lk);
#pragma unroll
            for (int i = 0; i < MF; ++i)
#pragma unroll
                for (int j = 0; j < NF; ++j)
                    acc[i][j] = __builtin_amdgcn_mfma_f32_16x16x32_bf16(af[i], bf[j], acc[i][j], 0, 0, 0);
        }
        __syncthreads();
    }

    const int bb4 = ((m_base >> 11) << 2) + 2;   // halo row shift (block-uniform)
#pragma unroll
    for (int i = 0; i < MF; ++i)
#pragma unroll
        for (int j = 0; j < NF; ++j)
#pragma unroll
            for (int jj = 0; jj < 4; ++jj) {
                const int r = m_base + wr * (BM / 2) + i * 16 + 4 * lk + jj;
                const int n = n_base + wc * (BN / 2) + j * 16 + l15;
                float v = acc[i][j][jj];
                if (p.act) v = fast_tanh(v);
                if (p.outF) p.outF[(size_t)r * p.ldoF + n] = v;
                if (p.outB) {
                    const int rr = p.outB_halo ? (r + bb4) : r;
                    p.outB[(size_t)rr * p.ldoB + n] = f2b(v);
                }
            }
}

// ---------------- fused 3-branch conv (as GEMM over taps), 128x128 tiles ----------------
// grid: (MTOK/128, 6); y -> branch = y>>1 (k=1/3/5), col-tile = y&1

struct ConvP {
    const ushort* Xh;          // [B][SH][768] bf16, halo'd
    const ushort* w0;          // [256][768]
    const ushort* w1;          // [256][2304]
    const ushort* w2;          // [256][3840]
    ushort* out;               // bf16 [MTOK][768]
};

__global__ __launch_bounds__(256) void conv_lds(ConvP p) {
    __shared__ __align__(16) ushort As[128 * 64];
    __shared__ __align__(16) ushort Bs[128 * 64];
    const int tid = threadIdx.x;
    const int w = tid >> 6, lane = tid & 63;
    const int l15 = lane & 15, lk = lane >> 4;
    const int m_base = blockIdx.x * 128;
    const int branch = blockIdx.y >> 1;            // 0,1,2 -> k=1,3,5
    const int c0loc = (blockIdx.y & 1) * 128;      // within branch's 256 channels
    const int coloff = branch * 256 + c0loc;
    const int bb = m_base >> 11;
    const int arow0 = m_base + 4 * bb + (2 - branch);
    const ushort* Wt = (branch == 0) ? p.w0 : (branch == 1) ? p.w1 : p.w2;
    const int Ktot = 768 * (2 * branch + 1);
    const int wr = w >> 1, wc = w & 1;
    f32x4 acc[4][4] = {};
    const int srow = lane >> 3;
    const int scol = (lane & 7) * 8;
    const int ntap = 2 * branch + 1;

    for (int t = 0; t < ntap; ++t) {
        const ushort* Ab = p.Xh + (size_t)(arow0 + t) * 768;
        const ushort* Wb = Wt + t * 768;
        for (int hs = 0; hs < 12; ++hs) {
            const int h0 = hs << 6;
#pragma unroll
            for (int q = 0; q < 4; ++q) {
                const int r = w * 32 + q * 8;
                gload16(Ab + (size_t)(r + srow) * 768 + h0 + scol, As + r * 64);
            }
#pragma unroll
            for (int q = 0; q < 4; ++q) {
                const int r = w * 32 + q * 8;
                gload16(Wb + (size_t)(c0loc + r + srow) * Ktot + h0 + scol, Bs + r * 64);
            }
            __syncthreads();
#pragma unroll
            for (int ks = 0; ks < 2; ++ks) {
                short8 af[4], bf[4];
#pragma unroll
                for (int i = 0; i < 4; ++i)
                    af[i] = *(const short8*)(As + (wr * 64 + i * 16 + l15) * 64 + ks * 32 + 8 * lk);
#pragma unroll
                for (int j = 0; j < 4; ++j)
                    bf[j] = *(const short8*)(Bs + (wc * 64 + j * 16 + l15) * 64 + ks * 32 + 8 * lk);
#pragma unroll
                for (int i = 0; i < 4; ++i)
#pragma unroll
                    for (int j = 0; j < 4; ++j)
                        acc[i][j] = __builtin_amdgcn_mfma_f32_16x16x32_bf16(af[i], bf[j], acc[i][j], 0, 0, 0);
            }
            __syncthreads();
        }
    }

#pragma unroll
    for (int i = 0; i < 4; ++i)
#pragma unroll
        for (int j = 0; j < 4; ++j)
#pragma unroll
            for (int jj = 0; jj < 4; ++jj) {
                const int r = m_base + wr * 64 + i * 16 + 4 * lk + jj;
                const int n = coloff + wc * 64 + j * 16 + l15;
                p.out[(size_t)r * H_ + n] = f2b(acc[i][j][jj]);
            }
}

// ---------------- LayerNorm(conv_out + residual) -> bf16 ----------------

__global__ __launch_bounds__(256) void k_ln(const ushort* __restrict__ conv,
                                            const float* __restrict__ rep,
                                            const float* __restrict__ gw,
                                            const float* __restrict__ bw,
                                            ushort* __restrict__ out) {
    const int row = blockIdx.x;
    const ushort* cp = conv + (size_t)row * H_;
    const float*  rp = rep  + (size_t)row * H_;
    const int tid = threadIdx.x;
    float v[3];
#pragma unroll
    for (int q = 0; q < 3; ++q) { int h = tid + q * 256; v[q] = b2f(cp[h]) + rp[h]; }
    float s1 = v[0] + v[1] + v[2];
    float s2 = v[0] * v[0] + v[1] * v[1] + v[2] * v[2];
#pragma unroll
    for (int off = 32; off; off >>= 1) { s1 += __shfl_xor(s1, off); s2 += __shfl_xor(s2, off); }
    __shared__ float sh[8];
    const int wid = tid >> 6, lane = tid & 63;
    if (lane == 0) { sh[wid] = s1; sh[4 + wid] = s2; }
    __syncthreads();
    s1 = sh[0] + sh[1] + sh[2] + sh[3];
    s2 = sh[4] + sh[5] + sh[6] + sh[7];
    const float mu  = s1 * (1.f / H_);
    const float var = s2 * (1.f / H_) - mu * mu;
    const float rs  = rsqrtf(var + 1e-5f);
    ushort* op = out + (size_t)row * H_;
#pragma unroll
    for (int q = 0; q < 3; ++q) {
        int h = tid + q * 256;
        op[h] = f2b((v[q] - mu) * rs * gw[h] + bw[h]);
    }
}

// ---------------- row-normalize location -> bf16 ----------------

__global__ __launch_bounds__(256) void k_normed(const float* __restrict__ loc, ushort* __restrict__ out) {
    const int wid = threadIdx.x >> 6, lane = threadIdx.x & 63;
    const int row = blockIdx.x * 4 + wid;
    const float* lp = loc + (size_t)row * K_;
    const float x0 = lp[lane], x1 = lp[lane + 64];
    float ss = x0 * x0 + x1 * x1;
#pragma unroll
    for (int off = 32; off; off >>= 1) ss += __shfl_xor(ss, off);
    const float sc = 1.f / fmaxf(sqrtf(ss), 1e-8f);
    ushort* op = out + (size_t)row * K_;
    op[lane] = f2b(x0 * sc);
    op[lane + 64] = f2b(x1 * sc);
}

// ---------------- banded cosine-sim ----------------

__global__ __launch_bounds__(256) void k_sim(const ushort* __restrict__ normed,
                                             const int* __restrict__ Lp,
                                             float* __restrict__ dis) {
    const int wid = threadIdx.x >> 6, lane = threadIdx.x & 63;
    const int l15 = lane & 15, lk = lane >> 4;
    const int b  = blockIdx.z;
    const int i0 = blockIdx.x * 64 + wid * 16;
    const int j0 = blockIdx.y * 64;
    const ushort* nb = normed + (size_t)b * S_ * K_;
    f32x4 acc[4] = {};
#pragma unroll
    for (int kt = 0; kt < 4; ++kt) {
        const int kk = kt * 32;
        const short8 a = *(const short8*)(nb + (size_t)(i0 + l15) * K_ + kk + 8 * lk);
#pragma unroll
        for (int j = 0; j < 4; ++j) {
            const short8 bfr = *(const short8*)(nb + (size_t)(j0 + j * 16 + l15) * K_ + kk + 8 * lk);
            acc[j] = __builtin_amdgcn_mfma_f32_16x16x32_bf16(a, bfr, acc[j], 0, 0, 0);
        }
    }
    const int L = *Lp;
    float* dp = dis + (size_t)b * S_ * S_;
#pragma unroll
    for (int j = 0; j < 4; ++j) {
#pragma unroll
        for (int jj = 0; jj < 4; ++jj) {
            const int i  = i0 + 4 * lk + jj;
            const int jc = j0 + j * 16 + l15;
            const int d  = jc - i;
            dp[(size_t)i * S_ + jc] = (d >= 1 && d <= L) ? acc[j][jj] : 0.f;
        }
    }
}

// ---------------- tags ----------------

__global__ void k_tags(const float* __restrict__ mask, const int* __restrict__ Lp,
                       float* __restrict__ tags) {
    const int L = *Lp;
    size_t i4 = (size_t)blockIdx.x * blockDim.x + threadIdx.x;
    const size_t stride = (size_t)gridDim.x * blockDim.x;
    const size_t n4 = (size_t)B_ * S_ * S_ / 4;
    for (; i4 < n4; i4 += stride) {
        const size_t idx = i4 * 4;
        const int b = (int)(idx / ((size_t)S_ * S_));
        const int rem = (int)(idx % ((size_t)S_ * S_));
        const int i = rem / S_;
        const int j = rem % S_;
        const float mi = mask[b * S_ + i];
        const float4 mj = *(const float4*)(mask + b * S_ + j);
        float4 o;
        int d0 = j - i;
        o.x = (d0 + 0 >= 1 && d0 + 0 <= L) ? mi * mj.x : 0.f;
        o.y = (d0 + 1 >= 1 && d0 + 1 <= L) ? mi * mj.y : 0.f;
        o.z = (d0 + 2 >= 1 && d0 + 2 <= L) ? mi * mj.z : 0.f;
        o.w = (d0 + 3 >= 1 && d0 + 3 <= L) ? mi * mj.w : 0.f;
        *(float4*)(tags + idx) = o;
    }
}

// ---------------- host launch ----------------

extern "C" void kernel_launch(void* const* d_in, const int* in_sizes, int n_in,
                              void* d_out, int out_size, void* d_ws, size_t ws_size,
                              hipStream_t stream) {
    const float* rep  = (const float*)d_in[0];
    const float* mask = (const float*)d_in[1];
    const float* ew1  = (const float*)d_in[2];
    const float* ew3  = (const float*)d_in[3];
    const float* ew5  = (const float*)d_in[4];
    const float* lng  = (const float*)d_in[5];
    const float* lnb  = (const float*)d_in[6];
    const float* elin = (const float*)d_in[7];
    const float* etr  = (const float*)d_in[8];
    const float* dtr  = (const float*)d_in[9];
    const float* dw1  = (const float*)d_in[10];
    const float* dw3  = (const float*)d_in[11];
    const float* dw5  = (const float*)d_in[12];
    const float* dlin = (const float*)d_in[13];
    const float* olin = (const float*)d_in[14];

    float* out_loc = (float*)d_out;
    float* out_dis = out_loc + (size_t)B_ * S_ * K_;
    float* out_tag = out_dis + (size_t)B_ * S_ * S_;
    float* out_dec = out_tag + (size_t)B_ * S_ * S_;

    char* ws = (char*)d_ws;
    size_t off = 0;
    auto alloc = [&](size_t bytes) -> char* {
        char* p = ws + off;
        off += (bytes + 255) & ~(size_t)255;
        return p;
    };
    int*    Lp    = (int*)alloc(256);
    ushort* Xh    = (ushort*)alloc((size_t)B_ * SH_ * H_ * 2);  // enc input / dec d0 (halo'd)
    ushort* wte1  = (ushort*)alloc((size_t)C_ * 768 * 2);
    ushort* wte3  = (ushort*)alloc((size_t)C_ * 2304 * 2);
    ushort* wte5  = (ushort*)alloc((size_t)C_ * 3840 * 2);
    ushort* wtd1  = (ushort*)alloc((size_t)C_ * 768 * 2);
    ushort* wtd3  = (ushort*)alloc((size_t)C_ * 2304 * 2);
    ushort* wtd5  = (ushort*)alloc((size_t)C_ * 3840 * 2);
    ushort* welin = (ushort*)alloc((size_t)H_ * H_ * 2);
    ushort* wetr  = (ushort*)alloc((size_t)K_ * H_ * 2);
    ushort* wdtr  = (ushort*)alloc((size_t)H_ * K_ * 2);
    ushort* wdlin = (ushort*)alloc((size_t)H_ * H_ * 2);
    ushort* wolin = (ushort*)alloc((size_t)H_ * H_ * 2);
    ushort* bufB  = (ushort*)alloc((size_t)MTOK * H_ * 2);
    ushort* bufC  = (ushort*)alloc((size_t)MTOK * H_ * 2);
    ushort* bufD  = (ushort*)alloc((size_t)MTOK * H_ * 2);
    ushort* bufL  = (ushort*)alloc((size_t)MTOK * K_ * 2);
    ushort* bufN  = (ushort*)alloc((size_t)MTOK * K_ * 2);
    if (ws_size < off) return;

    // 1. max_act_len + halo'd bf16 input
    k_maxlen<<<1, 256, 0, stream>>>(mask, Lp);
    k_build_xh<<<2048, 256, 0, stream>>>(rep, Xh);

    // 2. all weight conversions, one launch
    CvtAll ca;
    ca.e[0]  = { ew1,  wte1, 768 * C_,  768 };
    ca.e[1]  = { ew3,  wte3, 2304 * C_, 2304 };
    ca.e[2]  = { ew5,  wte5, 3840 * C_, 3840 };
    ca.e[3]  = { dw1,  wtd1, 768 * C_,  768 };
    ca.e[4]  = { dw3,  wtd3, 2304 * C_, 2304 };
    ca.e[5]  = { dw5,  wtd5, 3840 * C_, 3840 };
    ca.e[6]  = { elin, welin, H_ * H_, 0 };
    ca.e[7]  = { etr,  wetr,  K_ * H_, 0 };
    ca.e[8]  = { dtr,  wdtr,  H_ * K_, 0 };
    ca.e[9]  = { dlin, wdlin, H_ * H_, 0 };
    ca.e[10] = { olin, wolin, H_ * H_, 0 };
    k_cvt_all<<<dim3(256, 11), 256, 0, stream>>>(ca);

    // 3. encoder convs (fused 3 branches) -> bufB
    {
        ConvP p{ Xh, wte1, wte3, wte5, bufB };
        conv_lds<<<dim3(MTOK / 128, 6), 256, 0, stream>>>(p);
    }
    // 4. LN(conv + rep) -> bufC
    k_ln<<<MTOK, 256, 0, stream>>>(bufB, rep, lng, lnb, bufC);
    // 5. h2 = tanh(h_ln @ enc_lin^T) -> bufD
    {
        GemmP p{}; p.A = bufC; p.lda = H_; p.Wt = welin; p.Ktot = H_;
        p.outB = bufD; p.ldoB = H_; p.act = 1;
        gemm_lds<128, 128><<<dim3(MTOK / 128, H_ / 128), 256, 0, stream>>>(p);
    }
    // 6. location = h2 @ enc_tr^T -> out_loc (f32) + bufL (bf16)
    {
        GemmP p{}; p.A = bufD; p.lda = H_; p.Wt = wetr; p.Ktot = H_;
        p.outF = out_loc; p.ldoF = K_; p.outB = bufL; p.ldoB = K_;
        gemm_lds<64, 128><<<dim3(MTOK / 64, 1), 256, 0, stream>>>(p);
    }
    // 7. normed -> bufN
    k_normed<<<MTOK / 4, 256, 0, stream>>>(out_loc, bufN);
    // 8. d0 = location @ dec_tr^T -> Xh interior (halo rows stay zero from k_build_xh)
    {
        GemmP p{}; p.A = bufL; p.lda = K_; p.Wt = wdtr; p.Ktot = K_;
        p.outB = Xh; p.ldoB = H_; p.outB_halo = 1;
        gemm_lds<128, 128><<<dim3(MTOK / 128, H_ / 128), 256, 0, stream>>>(p);
    }
    // 9. decoder convs -> bufB
    {
        ConvP p{ Xh, wtd1, wtd3, wtd5, bufB };
        conv_lds<<<dim3(MTOK / 128, 6), 256, 0, stream>>>(p);
    }
    // 10. d2 = tanh(d1 @ dec_lin^T) -> bufC
    {
        GemmP p{}; p.A = bufB; p.lda = H_; p.Wt = wdlin; p.Ktot = H_;
        p.outB = bufC; p.ldoB = H_; p.act = 1;
        gemm_lds<128, 128><<<dim3(MTOK / 128, H_ / 128), 256, 0, stream>>>(p);
    }
    // 11. decode_out = d2 @ out_lin^T -> out_dec (f32)
    {
        GemmP p{}; p.A = bufC; p.lda = H_; p.Wt = wolin; p.Ktot = H_;
        p.outF = out_dec; p.ldoF = H_;
        gemm_lds<128, 128><<<dim3(MTOK / 128, H_ / 128), 256, 0, stream>>>(p);
    }
    // 12. banded cosine sim -> out_dis
    k_sim<<<dim3(S_ / 64, S_ / 64, B_), 256, 0, stream>>>(bufN, Lp, out_dis);
    // 13. tags -> out_tag
    k_tags<<<4096, 256, 0, stream>>>(mask, Lp, out_tag);
}

// Round 3
// 479.483 us; speedup vs baseline: 2.4147x; 1.1218x over previous
//
#include <hip/hip_runtime.h>

#define B_   8
#define S_   2048
#define H_   768
#define K_   128
#define C_   256
#define SH_  2052              // S + 4 halo rows (2 each side)
#define MTOK (B_*S_)           // 16384 tokens

typedef __attribute__((ext_vector_type(8))) short short8;
typedef __attribute__((ext_vector_type(4))) float f32x4;

typedef __attribute__((address_space(1))) const void gvoid;
typedef __attribute__((address_space(3))) void lvoid;

__device__ __forceinline__ void gload16(const void* g, void* l) {
    __builtin_amdgcn_global_load_lds((gvoid*)g, (lvoid*)l, 16, 0, 0);
}

__device__ __forceinline__ ushort f2b(float f) {
    union { float f; unsigned u; } v; v.f = f;
    unsigned r = v.u + 0x7fffu + ((v.u >> 16) & 1u);   // RNE
    return (ushort)(r >> 16);
}
__device__ __forceinline__ float b2f(ushort u) {
    union { unsigned u; float f; } v; v.u = ((unsigned)u) << 16;
    return v.f;
}
__device__ __forceinline__ float fast_tanh(float x) {
    float e = __expf(2.f * x);
    return 1.f - 2.f / (e + 1.f);
}

// ---------------- small prep kernels ----------------

__global__ void k_maxlen(const float* __restrict__ mask, int* Lp) {
    __shared__ float sh[256];
    float mx = 0.f;
    for (int b = 0; b < B_; ++b) {
        float s = 0.f;
        for (int i = threadIdx.x; i < S_; i += 256) s += mask[b * S_ + i];
        sh[threadIdx.x] = s;
        __syncthreads();
        for (int off = 128; off; off >>= 1) {
            if (threadIdx.x < off) sh[threadIdx.x] += sh[threadIdx.x + off];
            __syncthreads();
        }
        if (threadIdx.x == 0) mx = fmaxf(mx, sh[0]);
        __syncthreads();
    }
    if (threadIdx.x == 0) *Lp = (int)mx;
}

// build halo'd bf16 copy of representation (vectorized x4)
__global__ void k_build_xh(const float* __restrict__ rep, ushort* __restrict__ xh) {
    int i = blockIdx.x * blockDim.x + threadIdx.x;
    const int stride = gridDim.x * blockDim.x;
    const int n4 = B_ * SH_ * H_ / 4;
    for (; i < n4; i += stride) {
        const int idx = i * 4;
        const int h = idx % H_;
        const int rs = idx / H_;
        const int s = rs % SH_;
        const int b = rs / SH_;
        ushort4 o; o.x = 0; o.y = 0; o.z = 0; o.w = 0;
        if (s >= 2 && s < S_ + 2) {
            const float4 v = *(const float4*)(rep + ((size_t)b * S_ + (s - 2)) * H_ + h);
            o.x = f2b(v.x); o.y = f2b(v.y); o.z = f2b(v.z); o.w = f2b(v.w);
        }
        *(ushort4*)(xh + idx) = o;
    }
}

// fused weight conversions: 11 entries in one launch
struct CvtE { const float* src; ushort* dst; int n; int kh; };  // kh=0: copy, else [KH][C]->[C][KH]
struct CvtAll { CvtE e[11]; };

__global__ void k_cvt_all(CvtAll a) {
    const CvtE e = a.e[blockIdx.y];
    int i = blockIdx.x * blockDim.x + threadIdx.x;
    const int stride = gridDim.x * blockDim.x;
    for (; i < e.n; i += stride) {
        if (e.kh) {
            const int c = i / e.kh;
            const int r = i - c * e.kh;
            e.dst[i] = f2b(e.src[r * C_ + c]);
        } else {
            e.dst[i] = f2b(e.src[i]);
        }
    }
}

// ---------------- 8-wave deep-pipelined MFMA GEMM (256-col tiles, counted vmcnt) ----------
// out[m,n] = act( sum_k A[m,k] * Wt[n,k] ), BN = 256, BK = 64, 512 threads.
// LDS double-buffered; stage of tile t+2 is issued only after a barrier that all
// waves reach with their ds_reads of that buffer complete; vmcnt never drains to 0
// mid-loop (tile t+1's loads stay in flight across tile t's compute).

struct G8P {
    const ushort* A;
    const ushort* W0;   // linear: the weight; conv: k=1 branch
    const ushort* W1;   // conv: k=3 branch
    const ushort* W2;   // conv: k=5 branch
    int Ktot;           // linear only
    int lda;
    ushort* outB; int ldoB;
    float*  outF; int ldoF;
    int act;
    int nMtiles;        // conv: MTOK/BM
};

template<int MFR, bool CONV>
__global__ __launch_bounds__(512, 2) void gemm8(G8P p) {
    constexpr int BM = MFR * 32;
    constexpr int ASEGS = BM * 8;          // 16B segments in A tile (BM rows x 128B)
    constexpr int BSEGS = 2048;            // 256 rows x 128B
    constexpr int AL = ASEGS / 512;        // per-thread A loads per tile (4 or 2)
    constexpr int BL = 4;

    __shared__ __align__(16) ushort lds[2][(ASEGS + BSEGS) * 8];

    const int tid = threadIdx.x;
    const int w = tid >> 6, lane = tid & 63;
    const int l15 = lane & 15, lk = lane >> 4;
    const int wr = w >> 2, wc = w & 3;
    const int axor = l15 & 7;

    int m_base, n_base, nt, Ktot, arow0;
    const ushort* Wt;
    if (CONV) {
        const int nM = p.nMtiles;
        int idx = blockIdx.x;
        int br;
        if (idx < nM) br = 2;                         // k=5 blocks dispatch first (long pole)
        else if (idx < 2 * nM) { br = 1; idx -= nM; }
        else { br = 0; idx -= 2 * nM; }
        m_base = idx * BM;
        n_base = br * 256;
        nt = 12 * (2 * br + 1);
        Ktot = 768 * (2 * br + 1);
        Wt = (br == 0) ? p.W0 : (br == 1) ? p.W1 : p.W2;
        arow0 = m_base + ((m_base >> 11) << 2) + (2 - br);   // halo'd row base
    } else {
        m_base = blockIdx.x * BM;
        n_base = blockIdx.y * 256;
        nt = p.Ktot >> 6;
        Ktot = p.Ktot;
        Wt = p.W0;
        arow0 = m_base;
    }

    auto stage = [&](int kt, int bufi) {
        const int kk = kt << 6;
        int rowoff = 0, h0 = kk;
        if (CONV) { const int tap = kt / 12; rowoff = tap; h0 = (kt - tap * 12) << 6; }
        ushort* Ab = &lds[bufi][0];
        ushort* Bb = &lds[bufi][ASEGS * 8];
#pragma unroll
        for (int q = 0; q < AL; ++q) {
            const int seg = q * 512 + tid;
            const int row = seg >> 3;
            const int slot = (seg & 7) ^ (row & 7);     // pre-inverse-swizzled source (T2)
            gload16(p.A + (size_t)(arow0 + rowoff + row) * p.lda + h0 + slot * 8, Ab + seg * 8);
        }
#pragma unroll
        for (int q = 0; q < BL; ++q) {
            const int seg = q * 512 + tid;
            const int row = seg >> 3;
            const int slot = (seg & 7) ^ (row & 7);
            const int wrow = (CONV ? 0 : n_base) + row;
            gload16(Wt + (size_t)wrow * Ktot + kk + slot * 8, Bb + seg * 8);
        }
    };

    f32x4 acc[MFR][4] = {};

    stage(0, 0);
    stage(1, 1);

    for (int t = 0; t < nt; ++t) {
        const ushort* Ab = &lds[t & 1][0];
        const ushort* Bb = &lds[t & 1][ASEGS * 8];
        if (t + 1 < nt) {
            if constexpr (MFR == 8) asm volatile("s_waitcnt vmcnt(8)" ::: "memory");
            else                    asm volatile("s_waitcnt vmcnt(6)" ::: "memory");
        } else {
            asm volatile("s_waitcnt vmcnt(0)" ::: "memory");
        }
        __builtin_amdgcn_sched_barrier(0);
        asm volatile("s_barrier" ::: "memory");     // tile t resident for all waves
        __builtin_amdgcn_sched_barrier(0);

        short8 bf[4][2];
#pragma unroll
        for (int ni = 0; ni < 4; ++ni) {
#pragma unroll
            for (int ks = 0; ks < 2; ++ks) {
                const int off = (wc * 64 + ni * 16 + l15) * 64 + ((((ks << 2) | lk) ^ axor) << 3);
                bf[ni][ks] = *(const short8*)(Bb + off);
            }
        }
#pragma unroll
        for (int g = 0; g < MFR / 4; ++g) {
            short8 af[4][2];
#pragma unroll
            for (int mi = 0; mi < 4; ++mi) {
#pragma unroll
                for (int ks = 0; ks < 2; ++ks) {
                    const int off = (wr * (BM / 2) + (g * 4 + mi) * 16 + l15) * 64 + ((((ks << 2) | lk) ^ axor) << 3);
                    af[mi][ks] = *(const short8*)(Ab + off);
                }
            }
            asm volatile("s_waitcnt lgkmcnt(0)" ::: "memory");
            __builtin_amdgcn_sched_barrier(0);
            __builtin_amdgcn_s_setprio(1);
#pragma unroll
            for (int mi = 0; mi < 4; ++mi)
#pragma unroll
                for (int ni = 0; ni < 4; ++ni) {
                    acc[g * 4 + mi][ni] = __builtin_amdgcn_mfma_f32_16x16x32_bf16(af[mi][0], bf[ni][0], acc[g * 4 + mi][ni], 0, 0, 0);
                    acc[g * 4 + mi][ni] = __builtin_amdgcn_mfma_f32_16x16x32_bf16(af[mi][1], bf[ni][1], acc[g * 4 + mi][ni], 0, 0, 0);
                }
            __builtin_amdgcn_s_setprio(0);
        }
        __builtin_amdgcn_sched_barrier(0);
        asm volatile("s_barrier" ::: "memory");     // all waves done reading buf[t&1]
        __builtin_amdgcn_sched_barrier(0);
        if (t + 2 < nt) stage(t + 2, t & 1);        // overwrite is now safe; lands under MFMA
    }

#pragma unroll
    for (int fi = 0; fi < MFR; ++fi)
#pragma unroll
        for (int ni = 0; ni < 4; ++ni)
#pragma unroll
            for (int jj = 0; jj < 4; ++jj) {
                const int r = m_base + wr * (BM / 2) + fi * 16 + 4 * lk + jj;
                const int n = n_base + wc * 64 + ni * 16 + l15;
                float v = acc[fi][ni][jj];
                if (p.act) v = fast_tanh(v);
                if (p.outF) p.outF[(size_t)r * p.ldoF + n] = v;
                if (p.outB) p.outB[(size_t)r * p.ldoB + n] = f2b(v);
            }
}

// ---------------- small LDS-staged GEMM (m97 2-phase) for N=128 / K=128 cases ----------

struct GemmP {
    const ushort* A;
    const ushort* Wt;
    int Ktot;
    int lda;
    ushort* outB;
    int ldoB;
    int outB_halo;      // row' = r + 4*(r>>11) + 2
    float* outF;
    int ldoF;
    int act;
};

template<int BM, int BN>
__global__ __launch_bounds__(256) void gemm_lds(GemmP p) {
    constexpr int MF = BM / 32;
    constexpr int NF = BN / 32;
    __shared__ __align__(16) ushort As[BM * 64];
    __shared__ __align__(16) ushort Bs[BN * 64];
    const int tid = threadIdx.x;
    const int w = tid >> 6, lane = tid & 63;
    const int l15 = lane & 15, lk = lane >> 4;
    const int m_base = blockIdx.x * BM;
    const int n_base = blockIdx.y * BN;
    const int wr = w >> 1, wc = w & 1;
    f32x4 acc[MF][NF] = {};
    const int srow = lane >> 3;
    const int scol = (lane & 7) * 8;
    const int nk = p.Ktot >> 6;

    for (int kt = 0; kt < nk; ++kt) {
        const int kk = kt << 6;
#pragma unroll
        for (int q = 0; q < BM / 32; ++q) {
            const int r = w * (BM / 4) + q * 8;
            gload16(p.A + (size_t)(m_base + r + srow) * p.lda + kk + scol, As + r * 64);
        }
#pragma unroll
        for (int q = 0; q < BN / 32; ++q) {
            const int r = w * (BN / 4) + q * 8;
            gload16(p.Wt + (size_t)(n_base + r + srow) * p.Ktot + kk + scol, Bs + r * 64);
        }
        __syncthreads();
#pragma unroll
        for (int ks = 0; ks < 2; ++ks) {
            short8 af[MF], bfr[NF];
#pragma unroll
            for (int i = 0; i < MF; ++i)
                af[i] = *(const short8*)(As + (wr * (BM / 2) + i * 16 + l15) * 64 + ks * 32 + 8 * lk);
#pragma unroll
            for (int j = 0; j < NF; ++j)
                bfr[j] = *(const short8*)(Bs + (wc * (BN / 2) + j * 16 + l15) * 64 + ks * 32 + 8 * lk);
#pragma unroll
            for (int i = 0; i < MF; ++i)
#pragma unroll
                for (int j = 0; j < NF; ++j)
                    acc[i][j] = __builtin_amdgcn_mfma_f32_16x16x32_bf16(af[i], bfr[j], acc[i][j], 0, 0, 0);
        }
        __syncthreads();
    }

    const int bb4 = ((m_base >> 11) << 2) + 2;
#pragma unroll
    for (int i = 0; i < MF; ++i)
#pragma unroll
        for (int j = 0; j < NF; ++j)
#pragma unroll
            for (int jj = 0; jj < 4; ++jj) {
                const int r = m_base + wr * (BM / 2) + i * 16 + 4 * lk + jj;
                const int n = n_base + wc * (BN / 2) + j * 16 + l15;
                float v = acc[i][j][jj];
                if (p.act) v = fast_tanh(v);
                if (p.outF) p.outF[(size_t)r * p.ldoF + n] = v;
                if (p.outB) {
                    const int rr = p.outB_halo ? (r + bb4) : r;
                    p.outB[(size_t)rr * p.ldoB + n] = f2b(v);
                }
            }
}

// ---------------- LayerNorm(conv_out + residual) -> bf16 (vectorized, 192 thr/row) -----

__global__ __launch_bounds__(192) void k_ln(const ushort* __restrict__ conv,
                                            const float* __restrict__ rep,
                                            const float* __restrict__ gw,
                                            const float* __restrict__ bw,
                                            ushort* __restrict__ out) {
    const int row = blockIdx.x;
    const int tid = threadIdx.x;
    const int h = tid * 4;
    const ushort4 cv = *(const ushort4*)(conv + (size_t)row * H_ + h);
    const float4  rv = *(const float4*)(rep + (size_t)row * H_ + h);
    float v[4] = { b2f(cv.x) + rv.x, b2f(cv.y) + rv.y, b2f(cv.z) + rv.z, b2f(cv.w) + rv.w };
    float s1 = v[0] + v[1] + v[2] + v[3];
    float s2 = v[0]*v[0] + v[1]*v[1] + v[2]*v[2] + v[3]*v[3];
#pragma unroll
    for (int off = 32; off; off >>= 1) { s1 += __shfl_xor(s1, off); s2 += __shfl_xor(s2, off); }
    __shared__ float sh[6];
    const int wid = tid >> 6, lane = tid & 63;
    if (lane == 0) { sh[wid] = s1; sh[3 + wid] = s2; }
    __syncthreads();
    s1 = sh[0] + sh[1] + sh[2];
    s2 = sh[3] + sh[4] + sh[5];
    const float mu  = s1 * (1.f / H_);
    const float var = s2 * (1.f / H_) - mu * mu;
    const float rs  = rsqrtf(var + 1e-5f);
    const float4 gv = *(const float4*)(gw + h);
    const float4 bv = *(const float4*)(bw + h);
    ushort4 o;
    o.x = f2b((v[0] - mu) * rs * gv.x + bv.x);
    o.y = f2b((v[1] - mu) * rs * gv.y + bv.y);
    o.z = f2b((v[2] - mu) * rs * gv.z + bv.z);
    o.w = f2b((v[3] - mu) * rs * gv.w + bv.w);
    *(ushort4*)(out + (size_t)row * H_ + h) = o;
}

// ---------------- row-normalize location -> bf16 ----------------

__global__ __launch_bounds__(256) void k_normed(const float* __restrict__ loc, ushort* __restrict__ out) {
    const int wid = threadIdx.x >> 6, lane = threadIdx.x & 63;
    const int row = blockIdx.x * 4 + wid;
    const float* lp = loc + (size_t)row * K_;
    const float x0 = lp[lane], x1 = lp[lane + 64];
    float ss = x0 * x0 + x1 * x1;
#pragma unroll
    for (int off = 32; off; off >>= 1) ss += __shfl_xor(ss, off);
    const float sc = 1.f / fmaxf(sqrtf(ss), 1e-8f);
    ushort* op = out + (size_t)row * K_;
    op[lane] = f2b(x0 * sc);
    op[lane + 64] = f2b(x1 * sc);
}

// ---------------- banded cosine-sim ----------------

__global__ __launch_bounds__(256) void k_sim(const ushort* __restrict__ normed,
                                             const int* __restrict__ Lp,
                                             float* __restrict__ dis) {
    const int wid = threadIdx.x >> 6, lane = threadIdx.x & 63;
    const int l15 = lane & 15, lk = lane >> 4;
    const int b  = blockIdx.z;
    const int i0 = blockIdx.x * 64 + wid * 16;
    const int j0 = blockIdx.y * 64;
    const ushort* nb = normed + (size_t)b * S_ * K_;
    f32x4 acc[4] = {};
#pragma unroll
    for (int kt = 0; kt < 4; ++kt) {
        const int kk = kt * 32;
        const short8 a = *(const short8*)(nb + (size_t)(i0 + l15) * K_ + kk + 8 * lk);
#pragma unroll
        for (int j = 0; j < 4; ++j) {
            const short8 bfr = *(const short8*)(nb + (size_t)(j0 + j * 16 + l15) * K_ + kk + 8 * lk);
            acc[j] = __builtin_amdgcn_mfma_f32_16x16x32_bf16(a, bfr, acc[j], 0, 0, 0);
        }
    }
    const int L = *Lp;
    float* dp = dis + (size_t)b * S_ * S_;
#pragma unroll
    for (int j = 0; j < 4; ++j) {
#pragma unroll
        for (int jj = 0; jj < 4; ++jj) {
            const int i  = i0 + 4 * lk + jj;
            const int jc = j0 + j * 16 + l15;
            const int d  = jc - i;
            dp[(size_t)i * S_ + jc] = (d >= 1 && d <= L) ? acc[j][jj] : 0.f;
        }
    }
}

// ---------------- tags ----------------

__global__ void k_tags(const float* __restrict__ mask, const int* __restrict__ Lp,
                       float* __restrict__ tags) {
    const int L = *Lp;
    size_t i4 = (size_t)blockIdx.x * blockDim.x + threadIdx.x;
    const size_t stride = (size_t)gridDim.x * blockDim.x;
    const size_t n4 = (size_t)B_ * S_ * S_ / 4;
    for (; i4 < n4; i4 += stride) {
        const size_t idx = i4 * 4;
        const int b = (int)(idx / ((size_t)S_ * S_));
        const int rem = (int)(idx % ((size_t)S_ * S_));
        const int i = rem / S_;
        const int j = rem % S_;
        const float mi = mask[b * S_ + i];
        const float4 mj = *(const float4*)(mask + b * S_ + j);
        float4 o;
        int d0 = j - i;
        o.x = (d0 + 0 >= 1 && d0 + 0 <= L) ? mi * mj.x : 0.f;
        o.y = (d0 + 1 >= 1 && d0 + 1 <= L) ? mi * mj.y : 0.f;
        o.z = (d0 + 2 >= 1 && d0 + 2 <= L) ? mi * mj.z : 0.f;
        o.w = (d0 + 3 >= 1 && d0 + 3 <= L) ? mi * mj.w : 0.f;
        *(float4*)(tags + idx) = o;
    }
}

// ---------------- host launch ----------------

extern "C" void kernel_launch(void* const* d_in, const int* in_sizes, int n_in,
                              void* d_out, int out_size, void* d_ws, size_t ws_size,
                              hipStream_t stream) {
    const float* rep  = (const float*)d_in[0];
    const float* mask = (const float*)d_in[1];
    const float* ew1  = (const float*)d_in[2];
    const float* ew3  = (const float*)d_in[3];
    const float* ew5  = (const float*)d_in[4];
    const float* lng  = (const float*)d_in[5];
    const float* lnb  = (const float*)d_in[6];
    const float* elin = (const float*)d_in[7];
    const float* etr  = (const float*)d_in[8];
    const float* dtr  = (const float*)d_in[9];
    const float* dw1  = (const float*)d_in[10];
    const float* dw3  = (const float*)d_in[11];
    const float* dw5  = (const float*)d_in[12];
    const float* dlin = (const float*)d_in[13];
    const float* olin = (const float*)d_in[14];

    float* out_loc = (float*)d_out;
    float* out_dis = out_loc + (size_t)B_ * S_ * K_;
    float* out_tag = out_dis + (size_t)B_ * S_ * S_;
    float* out_dec = out_tag + (size_t)B_ * S_ * S_;

    char* ws = (char*)d_ws;
    size_t off = 0;
    auto alloc = [&](size_t bytes) -> char* {
        char* p = ws + off;
        off += (bytes + 255) & ~(size_t)255;
        return p;
    };
    int*    Lp    = (int*)alloc(256);
    ushort* Xh    = (ushort*)alloc((size_t)B_ * SH_ * H_ * 2);  // enc input / dec d0 (halo'd)
    ushort* wte1  = (ushort*)alloc((size_t)C_ * 768 * 2);
    ushort* wte3  = (ushort*)alloc((size_t)C_ * 2304 * 2);
    ushort* wte5  = (ushort*)alloc((size_t)C_ * 3840 * 2);
    ushort* wtd1  = (ushort*)alloc((size_t)C_ * 768 * 2);
    ushort* wtd3  = (ushort*)alloc((size_t)C_ * 2304 * 2);
    ushort* wtd5  = (ushort*)alloc((size_t)C_ * 3840 * 2);
    ushort* welin = (ushort*)alloc((size_t)H_ * H_ * 2);
    ushort* wetr  = (ushort*)alloc((size_t)K_ * H_ * 2);
    ushort* wdtr  = (ushort*)alloc((size_t)H_ * K_ * 2);
    ushort* wdlin = (ushort*)alloc((size_t)H_ * H_ * 2);
    ushort* wolin = (ushort*)alloc((size_t)H_ * H_ * 2);
    ushort* bufB  = (ushort*)alloc((size_t)MTOK * H_ * 2);
    ushort* bufC  = (ushort*)alloc((size_t)MTOK * H_ * 2);
    ushort* bufD  = (ushort*)alloc((size_t)MTOK * H_ * 2);
    ushort* bufL  = (ushort*)alloc((size_t)MTOK * K_ * 2);
    ushort* bufN  = (ushort*)alloc((size_t)MTOK * K_ * 2);
    if (ws_size < off) return;

    // 1. max_act_len + halo'd bf16 input
    k_maxlen<<<1, 256, 0, stream>>>(mask, Lp);
    k_build_xh<<<2048, 256, 0, stream>>>(rep, Xh);

    // 2. all weight conversions, one launch
    CvtAll ca;
    ca.e[0]  = { ew1,  wte1, 768 * C_,  768 };
    ca.e[1]  = { ew3,  wte3, 2304 * C_, 2304 };
    ca.e[2]  = { ew5,  wte5, 3840 * C_, 3840 };
    ca.e[3]  = { dw1,  wtd1, 768 * C_,  768 };
    ca.e[4]  = { dw3,  wtd3, 2304 * C_, 2304 };
    ca.e[5]  = { dw5,  wtd5, 3840 * C_, 3840 };
    ca.e[6]  = { elin, welin, H_ * H_, 0 };
    ca.e[7]  = { etr,  wetr,  K_ * H_, 0 };
    ca.e[8]  = { dtr,  wdtr,  H_ * K_, 0 };
    ca.e[9]  = { dlin, wdlin, H_ * H_, 0 };
    ca.e[10] = { olin, wolin, H_ * H_, 0 };
    k_cvt_all<<<dim3(256, 11), 256, 0, stream>>>(ca);

    // 3. encoder convs (fused 3 branches, k=5 first) -> bufB
    {
        G8P p{}; p.A = Xh; p.W0 = wte1; p.W1 = wte3; p.W2 = wte5;
        p.lda = H_; p.outB = bufB; p.ldoB = H_; p.nMtiles = MTOK / 128;
        gemm8<4, true><<<3 * (MTOK / 128), 512, 0, stream>>>(p);
    }
    // 4. LN(conv + rep) -> bufC
    k_ln<<<MTOK, 192, 0, stream>>>(bufB, rep, lng, lnb, bufC);
    // 5. h2 = tanh(h_ln @ enc_lin^T) -> bufD
    {
        G8P p{}; p.A = bufC; p.W0 = welin; p.Ktot = H_; p.lda = H_;
        p.outB = bufD; p.ldoB = H_; p.act = 1;
        gemm8<8, false><<<dim3(MTOK / 256, H_ / 256), 512, 0, stream>>>(p);
    }
    // 6. location = h2 @ enc_tr^T -> out_loc (f32) + bufL (bf16)
    {
        GemmP p{}; p.A = bufD; p.lda = H_; p.Wt = wetr; p.Ktot = H_;
        p.outF = out_loc; p.ldoF = K_; p.outB = bufL; p.ldoB = K_;
        gemm_lds<64, 128><<<dim3(MTOK / 64, 1), 256, 0, stream>>>(p);
    }
    // 7. normed -> bufN
    k_normed<<<MTOK / 4, 256, 0, stream>>>(out_loc, bufN);
    // 8. d0 = location @ dec_tr^T -> Xh interior (halo rows stay zero)
    {
        GemmP p{}; p.A = bufL; p.lda = K_; p.Wt = wdtr; p.Ktot = K_;
        p.outB = Xh; p.ldoB = H_; p.outB_halo = 1;
        gemm_lds<128, 128><<<dim3(MTOK / 128, H_ / 128), 256, 0, stream>>>(p);
    }
    // 9. decoder convs -> bufB
    {
        G8P p{}; p.A = Xh; p.W0 = wtd1; p.W1 = wtd3; p.W2 = wtd5;
        p.lda = H_; p.outB = bufB; p.ldoB = H_; p.nMtiles = MTOK / 128;
        gemm8<4, true><<<3 * (MTOK / 128), 512, 0, stream>>>(p);
    }
    // 10. d2 = tanh(d1 @ dec_lin^T) -> bufC
    {
        G8P p{}; p.A = bufB; p.W0 = wdlin; p.Ktot = H_; p.lda = H_;
        p.outB = bufC; p.ldoB = H_; p.act = 1;
        gemm8<8, false><<<dim3(MTOK / 256, H_ / 256), 512, 0, stream>>>(p);
    }
    // 11. decode_out = d2 @ out_lin^T -> out_dec (f32)
    {
        G8P p{}; p.A = bufC; p.W0 = wolin; p.Ktot = H_; p.lda = H_;
        p.outF = out_dec; p.ldoF = H_;
        gemm8<8, false><<<dim3(MTOK / 256, H_ / 256), 512, 0, stream>>>(p);
    }
    // 12. banded cosine sim -> out_dis
    k_sim<<<dim3(S_ / 64, S_ / 64, B_), 256, 0, stream>>>(bufN, Lp, out_dis);
    // 13. tags -> out_tag
    k_tags<<<4096, 256, 0, stream>>>(mask, Lp, out_tag);
}

// Round 4
// 447.696 us; speedup vs baseline: 2.5862x; 1.0710x over previous
//
#include <hip/hip_runtime.h>

#define B_   8
#define S_   2048
#define H_   768
#define K_   128
#define C_   256
#define SH_  2052              // S + 4 halo rows (2 each side)
#define MTOK (B_*S_)           // 16384 tokens

typedef __attribute__((ext_vector_type(8))) short short8;
typedef __attribute__((ext_vector_type(4))) float f32x4;

typedef __attribute__((address_space(1))) const void gvoid;
typedef __attribute__((address_space(3))) void lvoid;

__device__ __forceinline__ void gload16(const void* g, void* l) {
    __builtin_amdgcn_global_load_lds((gvoid*)g, (lvoid*)l, 16, 0, 0);
}

__device__ __forceinline__ ushort f2b(float f) {
    union { float f; unsigned u; } v; v.f = f;
    unsigned r = v.u + 0x7fffu + ((v.u >> 16) & 1u);   // RNE
    return (ushort)(r >> 16);
}
__device__ __forceinline__ float b2f(ushort u) {
    union { unsigned u; float f; } v; v.u = ((unsigned)u) << 16;
    return v.f;
}
__device__ __forceinline__ float fast_tanh(float x) {
    float e = __expf(2.f * x);
    return 1.f - 2.f / (e + 1.f);
}

// ---------------- small prep kernels ----------------

__global__ __launch_bounds__(512) void k_maxlen(const float* __restrict__ mask, int* Lp) {
    __shared__ float sh[8];
    const int tid = threadIdx.x;
    float mx = 0.f;
    for (int b = 0; b < B_; ++b) {
        const float4 v = ((const float4*)(mask + b * S_))[tid];
        float s = v.x + v.y + v.z + v.w;
#pragma unroll
        for (int off = 32; off; off >>= 1) s += __shfl_xor(s, off);
        if ((tid & 63) == 0) sh[tid >> 6] = s;
        __syncthreads();
        if (tid == 0) {
            float t = 0.f;
#pragma unroll
            for (int q = 0; q < 8; ++q) t += sh[q];
            mx = fmaxf(mx, t);
        }
        __syncthreads();
    }
    if (tid == 0) *Lp = (int)mx;
}

// build halo'd bf16 copy of representation (vectorized x4)
__global__ void k_build_xh(const float* __restrict__ rep, ushort* __restrict__ xh) {
    int i = blockIdx.x * blockDim.x + threadIdx.x;
    const int stride = gridDim.x * blockDim.x;
    const int n4 = B_ * SH_ * H_ / 4;
    for (; i < n4; i += stride) {
        const int idx = i * 4;
        const int h = idx % H_;
        const int rs = idx / H_;
        const int s = rs % SH_;
        const int b = rs / SH_;
        ushort4 o; o.x = 0; o.y = 0; o.z = 0; o.w = 0;
        if (s >= 2 && s < S_ + 2) {
            const float4 v = *(const float4*)(rep + ((size_t)b * S_ + (s - 2)) * H_ + h);
            o.x = f2b(v.x); o.y = f2b(v.y); o.z = f2b(v.z); o.w = f2b(v.w);
        }
        *(ushort4*)(xh + idx) = o;
    }
}

// fused weight conversions: 11 entries in one launch
struct CvtE { const float* src; ushort* dst; int n; int kh; };  // kh=0: copy, else [KH][C]->[C][KH]
struct CvtAll { CvtE e[11]; };

__global__ void k_cvt_all(CvtAll a) {
    const CvtE e = a.e[blockIdx.y];
    int i = blockIdx.x * blockDim.x + threadIdx.x;
    const int stride = gridDim.x * blockDim.x;
    for (; i < e.n; i += stride) {
        if (e.kh) {
            const int c = i / e.kh;
            const int r = i - c * e.kh;
            e.dst[i] = f2b(e.src[r * C_ + c]);
        } else {
            e.dst[i] = f2b(e.src[i]);
        }
    }
}

// ---------------- g3: 8-wave, 3-deep-ring, counted-vmcnt MFMA GEMM ----------------
// BM=128, BN=256, BK=64, 512 threads (8 waves as 2x4, each wave 64x64 output).
// One s_barrier per K-tile; stage(t+2) issued right after tile t's barrier into
// the ring buffer last read at tile t-1 (drained before that barrier). vmcnt(6)
// waits only tile t's own 6 loads; tile t+1's stay in flight. T2 XOR swizzle on
// both stage-source and ds_read; T5 setprio around each 16-MFMA cluster.

struct G3P {
    const ushort* A;
    const ushort* W0;   // linear: weight; conv: k=1 branch
    const ushort* W1;   // conv: k=3
    const ushort* W2;   // conv: k=5
    int Ktot;           // linear only
    int lda;
    ushort* outB; int ldoB;
    float*  outF; int ldoF;
    int act;
    int nMtiles;        // conv: MTOK/128
};

template<bool CONV>
__global__ __launch_bounds__(512, 2) void g3(G3P p) {
    constexpr int ASEG = 1024;               // 128 rows x 8 (16B segs)
    constexpr int BSEG = 2048;               // 256 rows x 8
    constexpr int BUFE = (ASEG + BSEG) * 8;  // ushorts per buffer (48 KB)
    __shared__ __align__(16) ushort lds[3][BUFE];

    const int tid = threadIdx.x;
    const int w = tid >> 6, lane = tid & 63;
    const int l15 = lane & 15, lk = lane >> 4;
    const int wr = w >> 2, wc = w & 3;       // 2 x 4 wave grid
    const int axor = l15 & 7;

    int m_base, n_base, nt, Ktot, arow0;
    const ushort* Wt;
    if (CONV) {
        const int nM = p.nMtiles;
        int idx = blockIdx.x;
        int br;
        if (idx < nM) br = 2;                          // k=5 first (long pole)
        else if (idx < 2 * nM) { br = 1; idx -= nM; }
        else { br = 0; idx -= 2 * nM; }
        m_base = idx * 128;
        n_base = br * 256;
        nt = 12 * (2 * br + 1);
        Ktot = 768 * (2 * br + 1);
        Wt = (br == 0) ? p.W0 : (br == 1) ? p.W1 : p.W2;
        arow0 = m_base + ((m_base >> 11) << 2) + (2 - br);   // halo'd row base
    } else {
        m_base = blockIdx.x * 128;
        n_base = blockIdx.y * 256;
        nt = p.Ktot >> 6;
        Ktot = p.Ktot;
        Wt = p.W0;
        arow0 = m_base;
    }

    // q in [0,6): q<2 -> A segment round, else B segment round
    auto stage1 = [&](int kt, int bufi, int q) {
        const int kk = kt << 6;
        int rowoff = 0, h0 = kk;
        if (CONV) { const int tap = kt / 12; rowoff = tap; h0 = (kt - tap * 12) << 6; }
        if (q < 2) {
            const int seg = q * 512 + tid;
            const int row = seg >> 3;
            const int slot = (seg & 7) ^ (row & 7);
            gload16(p.A + (size_t)(arow0 + rowoff + row) * p.lda + h0 + slot * 8,
                    &lds[bufi][seg * 8]);
        } else {
            const int seg = (q - 2) * 512 + tid;
            const int row = seg >> 3;
            const int slot = (seg & 7) ^ (row & 7);
            const int wrow = (CONV ? 0 : n_base) + row;
            gload16(Wt + (size_t)wrow * Ktot + kk + slot * 8,
                    &lds[bufi][ASEG * 8 + seg * 8]);
        }
    };
    auto stage = [&](int kt, int bufi) {
#pragma unroll
        for (int q = 0; q < 6; ++q) stage1(kt, bufi, q);
    };

    f32x4 acc[4][4] = {};

    stage(0, 0);
    stage(1, 1);

    int buf = 0;
    for (int t = 0; t < nt; ++t) {
        const ushort* Ab = &lds[buf][0];
        const ushort* Bb = &lds[buf][ASEG * 8];
        if (t + 1 < nt) asm volatile("s_waitcnt vmcnt(6)" ::: "memory");
        else            asm volatile("s_waitcnt vmcnt(0)" ::: "memory");
        __builtin_amdgcn_sched_barrier(0);
        asm volatile("s_barrier" ::: "memory");   // all waves: tile t resident, tile t-1 reads done
        __builtin_amdgcn_sched_barrier(0);

        int nbuf = buf + 2; if (nbuf >= 3) nbuf -= 3;
        const bool sb = (t + 2 < nt);

#pragma unroll
        for (int ks = 0; ks < 2; ++ks) {
            short8 bq[4], aq[4];
#pragma unroll
            for (int ni = 0; ni < 4; ++ni)
                bq[ni] = *(const short8*)(Bb + (wc * 64 + ni * 16 + l15) * 64 + ((((ks << 2) | lk) ^ axor) << 3));
#pragma unroll
            for (int mi = 0; mi < 4; ++mi)
                aq[mi] = *(const short8*)(Ab + (wr * 64 + mi * 16 + l15) * 64 + ((((ks << 2) | lk) ^ axor) << 3));
            if (sb) { stage1(t + 2, nbuf, 3 * ks); stage1(t + 2, nbuf, 3 * ks + 1); stage1(t + 2, nbuf, 3 * ks + 2); }
            asm volatile("s_waitcnt lgkmcnt(0)" ::: "memory");
            __builtin_amdgcn_sched_barrier(0);
            __builtin_amdgcn_s_setprio(1);
#pragma unroll
            for (int mi = 0; mi < 4; ++mi)
#pragma unroll
                for (int ni = 0; ni < 4; ++ni)
                    acc[mi][ni] = __builtin_amdgcn_mfma_f32_16x16x32_bf16(aq[mi], bq[ni], acc[mi][ni], 0, 0, 0);
            __builtin_amdgcn_s_setprio(0);
            __builtin_amdgcn_sched_barrier(0);
        }
        ++buf; if (buf == 3) buf = 0;
    }

#pragma unroll
    for (int mi = 0; mi < 4; ++mi)
#pragma unroll
        for (int ni = 0; ni < 4; ++ni)
#pragma unroll
            for (int jj = 0; jj < 4; ++jj) {
                const int r = m_base + wr * 64 + mi * 16 + 4 * lk + jj;
                const int n = n_base + wc * 64 + ni * 16 + l15;
                float v = acc[mi][ni][jj];
                if (p.act) v = fast_tanh(v);
                if (p.outF) p.outF[(size_t)r * p.ldoF + n] = v;
                if (p.outB) p.outB[(size_t)r * p.ldoB + n] = f2b(v);
            }
}

// ---------------- small LDS-staged GEMM (m97 2-phase) for N=128 / K=128 cases ----------

struct GemmP {
    const ushort* A;
    const ushort* Wt;
    int Ktot;
    int lda;
    ushort* outB;
    int ldoB;
    int outB_halo;      // row' = r + 4*(r>>11) + 2
    float* outF;
    int ldoF;
    int act;
};

template<int BM, int BN>
__global__ __launch_bounds__(256) void gemm_lds(GemmP p) {
    constexpr int MF = BM / 32;
    constexpr int NF = BN / 32;
    __shared__ __align__(16) ushort As[BM * 64];
    __shared__ __align__(16) ushort Bs[BN * 64];
    const int tid = threadIdx.x;
    const int w = tid >> 6, lane = tid & 63;
    const int l15 = lane & 15, lk = lane >> 4;
    const int m_base = blockIdx.x * BM;
    const int n_base = blockIdx.y * BN;
    const int wr = w >> 1, wc = w & 1;
    f32x4 acc[MF][NF] = {};
    const int srow = lane >> 3;
    const int scol = (lane & 7) * 8;
    const int nk = p.Ktot >> 6;

    for (int kt = 0; kt < nk; ++kt) {
        const int kk = kt << 6;
#pragma unroll
        for (int q = 0; q < BM / 32; ++q) {
            const int r = w * (BM / 4) + q * 8;
            gload16(p.A + (size_t)(m_base + r + srow) * p.lda + kk + scol, As + r * 64);
        }
#pragma unroll
        for (int q = 0; q < BN / 32; ++q) {
            const int r = w * (BN / 4) + q * 8;
            gload16(p.Wt + (size_t)(n_base + r + srow) * p.Ktot + kk + scol, Bs + r * 64);
        }
        __syncthreads();
#pragma unroll
        for (int ks = 0; ks < 2; ++ks) {
            short8 af[MF], bfr[NF];
#pragma unroll
            for (int i = 0; i < MF; ++i)
                af[i] = *(const short8*)(As + (wr * (BM / 2) + i * 16 + l15) * 64 + ks * 32 + 8 * lk);
#pragma unroll
            for (int j = 0; j < NF; ++j)
                bfr[j] = *(const short8*)(Bs + (wc * (BN / 2) + j * 16 + l15) * 64 + ks * 32 + 8 * lk);
#pragma unroll
            for (int i = 0; i < MF; ++i)
#pragma unroll
                for (int j = 0; j < NF; ++j)
                    acc[i][j] = __builtin_amdgcn_mfma_f32_16x16x32_bf16(af[i], bfr[j], acc[i][j], 0, 0, 0);
        }
        __syncthreads();
    }

    const int bb4 = ((m_base >> 11) << 2) + 2;
#pragma unroll
    for (int i = 0; i < MF; ++i)
#pragma unroll
        for (int j = 0; j < NF; ++j)
#pragma unroll
            for (int jj = 0; jj < 4; ++jj) {
                const int r = m_base + wr * (BM / 2) + i * 16 + 4 * lk + jj;
                const int n = n_base + wc * (BN / 2) + j * 16 + l15;
                float v = acc[i][j][jj];
                if (p.act) v = fast_tanh(v);
                if (p.outF) p.outF[(size_t)r * p.ldoF + n] = v;
                if (p.outB) {
                    const int rr = p.outB_halo ? (r + bb4) : r;
                    p.outB[(size_t)rr * p.ldoB + n] = f2b(v);
                }
            }
}

// ---------------- LayerNorm(conv_out + residual) -> bf16 (vectorized, 192 thr/row) -----

__global__ __launch_bounds__(192) void k_ln(const ushort* __restrict__ conv,
                                            const float* __restrict__ rep,
                                            const float* __restrict__ gw,
                                            const float* __restrict__ bw,
                                            ushort* __restrict__ out) {
    const int row = blockIdx.x;
    const int tid = threadIdx.x;
    const int h = tid * 4;
    const ushort4 cv = *(const ushort4*)(conv + (size_t)row * H_ + h);
    const float4  rv = *(const float4*)(rep + (size_t)row * H_ + h);
    float v[4] = { b2f(cv.x) + rv.x, b2f(cv.y) + rv.y, b2f(cv.z) + rv.z, b2f(cv.w) + rv.w };
    float s1 = v[0] + v[1] + v[2] + v[3];
    float s2 = v[0]*v[0] + v[1]*v[1] + v[2]*v[2] + v[3]*v[3];
#pragma unroll
    for (int off = 32; off; off >>= 1) { s1 += __shfl_xor(s1, off); s2 += __shfl_xor(s2, off); }
    __shared__ float sh[6];
    const int wid = tid >> 6, lane = tid & 63;
    if (lane == 0) { sh[wid] = s1; sh[3 + wid] = s2; }
    __syncthreads();
    s1 = sh[0] + sh[1] + sh[2];
    s2 = sh[3] + sh[4] + sh[5];
    const float mu  = s1 * (1.f / H_);
    const float var = s2 * (1.f / H_) - mu * mu;
    const float rs  = rsqrtf(var + 1e-5f);
    const float4 gv = *(const float4*)(gw + h);
    const float4 bv = *(const float4*)(bw + h);
    ushort4 o;
    o.x = f2b((v[0] - mu) * rs * gv.x + bv.x);
    o.y = f2b((v[1] - mu) * rs * gv.y + bv.y);
    o.z = f2b((v[2] - mu) * rs * gv.z + bv.z);
    o.w = f2b((v[3] - mu) * rs * gv.w + bv.w);
    *(ushort4*)(out + (size_t)row * H_ + h) = o;
}

// ---------------- row-normalize location -> bf16 ----------------

__global__ __launch_bounds__(256) void k_normed(const float* __restrict__ loc, ushort* __restrict__ out) {
    const int wid = threadIdx.x >> 6, lane = threadIdx.x & 63;
    const int row = blockIdx.x * 4 + wid;
    const float* lp = loc + (size_t)row * K_;
    const float x0 = lp[lane], x1 = lp[lane + 64];
    float ss = x0 * x0 + x1 * x1;
#pragma unroll
    for (int off = 32; off; off >>= 1) ss += __shfl_xor(ss, off);
    const float sc = 1.f / fmaxf(sqrtf(ss), 1e-8f);
    ushort* op = out + (size_t)row * K_;
    op[lane] = f2b(x0 * sc);
    op[lane + 64] = f2b(x1 * sc);
}

// ---------------- banded cosine-sim + tags (fused; band-skip for compute) --------------

__global__ __launch_bounds__(256) void k_simtags(const ushort* __restrict__ normed,
                                                 const float* __restrict__ mask,
                                                 const int* __restrict__ Lp,
                                                 float* __restrict__ dis,
                                                 float* __restrict__ tags) {
    const int wid = threadIdx.x >> 6, lane = threadIdx.x & 63;
    const int l15 = lane & 15, lk = lane >> 4;
    const int b   = blockIdx.z;
    const int i0b = blockIdx.x * 64;
    const int i0  = i0b + wid * 16;
    const int j0  = blockIdx.y * 64;
    const int L   = *Lp;
    f32x4 acc[4] = {};
    // any element in band?  max(j-i) = j0+63-i0b >= 1  and  min(j-i) = j0-(i0b+63) <= L
    if ((j0 + 63 >= i0b + 1) && (j0 <= i0b + 63 + L)) {
        const ushort* nb = normed + (size_t)b * S_ * K_;
#pragma unroll
        for (int kt = 0; kt < 4; ++kt) {
            const int kk = kt * 32;
            const short8 a = *(const short8*)(nb + (size_t)(i0 + l15) * K_ + kk + 8 * lk);
#pragma unroll
            for (int j = 0; j < 4; ++j) {
                const short8 bfr = *(const short8*)(nb + (size_t)(j0 + j * 16 + l15) * K_ + kk + 8 * lk);
                acc[j] = __builtin_amdgcn_mfma_f32_16x16x32_bf16(a, bfr, acc[j], 0, 0, 0);
            }
        }
    }
    const float* mb = mask + b * S_;
    float* dp = dis  + (size_t)b * S_ * S_;
    float* tp = tags + (size_t)b * S_ * S_;
#pragma unroll
    for (int j = 0; j < 4; ++j) {
#pragma unroll
        for (int jj = 0; jj < 4; ++jj) {
            const int i  = i0 + 4 * lk + jj;
            const int jc = j0 + j * 16 + l15;
            const int d  = jc - i;
            const bool band = (d >= 1 && d <= L);
            dp[(size_t)i * S_ + jc] = band ? acc[j][jj] : 0.f;
            tp[(size_t)i * S_ + jc] = band ? mb[i] * mb[jc] : 0.f;
        }
    }
}

// ---------------- host launch ----------------

extern "C" void kernel_launch(void* const* d_in, const int* in_sizes, int n_in,
                              void* d_out, int out_size, void* d_ws, size_t ws_size,
                              hipStream_t stream) {
    const float* rep  = (const float*)d_in[0];
    const float* mask = (const float*)d_in[1];
    const float* ew1  = (const float*)d_in[2];
    const float* ew3  = (const float*)d_in[3];
    const float* ew5  = (const float*)d_in[4];
    const float* lng  = (const float*)d_in[5];
    const float* lnb  = (const float*)d_in[6];
    const float* elin = (const float*)d_in[7];
    const float* etr  = (const float*)d_in[8];
    const float* dtr  = (const float*)d_in[9];
    const float* dw1  = (const float*)d_in[10];
    const float* dw3  = (const float*)d_in[11];
    const float* dw5  = (const float*)d_in[12];
    const float* dlin = (const float*)d_in[13];
    const float* olin = (const float*)d_in[14];

    float* out_loc = (float*)d_out;
    float* out_dis = out_loc + (size_t)B_ * S_ * K_;
    float* out_tag = out_dis + (size_t)B_ * S_ * S_;
    float* out_dec = out_tag + (size_t)B_ * S_ * S_;

    char* ws = (char*)d_ws;
    size_t off = 0;
    auto alloc = [&](size_t bytes) -> char* {
        char* p = ws + off;
        off += (bytes + 255) & ~(size_t)255;
        return p;
    };
    int*    Lp    = (int*)alloc(256);
    ushort* Xh    = (ushort*)alloc((size_t)B_ * SH_ * H_ * 2);  // enc input / dec d0 (halo'd)
    ushort* wte1  = (ushort*)alloc((size_t)C_ * 768 * 2);
    ushort* wte3  = (ushort*)alloc((size_t)C_ * 2304 * 2);
    ushort* wte5  = (ushort*)alloc((size_t)C_ * 3840 * 2);
    ushort* wtd1  = (ushort*)alloc((size_t)C_ * 768 * 2);
    ushort* wtd3  = (ushort*)alloc((size_t)C_ * 2304 * 2);
    ushort* wtd5  = (ushort*)alloc((size_t)C_ * 3840 * 2);
    ushort* welin = (ushort*)alloc((size_t)H_ * H_ * 2);
    ushort* wetr  = (ushort*)alloc((size_t)K_ * H_ * 2);
    ushort* wdtr  = (ushort*)alloc((size_t)H_ * K_ * 2);
    ushort* wdlin = (ushort*)alloc((size_t)H_ * H_ * 2);
    ushort* wolin = (ushort*)alloc((size_t)H_ * H_ * 2);
    ushort* bufB  = (ushort*)alloc((size_t)MTOK * H_ * 2);
    ushort* bufC  = (ushort*)alloc((size_t)MTOK * H_ * 2);
    ushort* bufD  = (ushort*)alloc((size_t)MTOK * H_ * 2);
    ushort* bufL  = (ushort*)alloc((size_t)MTOK * K_ * 2);
    ushort* bufN  = (ushort*)alloc((size_t)MTOK * K_ * 2);
    if (ws_size < off) return;

    // 1. max_act_len + halo'd bf16 input
    k_maxlen<<<1, 512, 0, stream>>>(mask, Lp);
    k_build_xh<<<2048, 256, 0, stream>>>(rep, Xh);

    // 2. all weight conversions, one launch
    CvtAll ca;
    ca.e[0]  = { ew1,  wte1, 768 * C_,  768 };
    ca.e[1]  = { ew3,  wte3, 2304 * C_, 2304 };
    ca.e[2]  = { ew5,  wte5, 3840 * C_, 3840 };
    ca.e[3]  = { dw1,  wtd1, 768 * C_,  768 };
    ca.e[4]  = { dw3,  wtd3, 2304 * C_, 2304 };
    ca.e[5]  = { dw5,  wtd5, 3840 * C_, 3840 };
    ca.e[6]  = { elin, welin, H_ * H_, 0 };
    ca.e[7]  = { etr,  wetr,  K_ * H_, 0 };
    ca.e[8]  = { dtr,  wdtr,  H_ * K_, 0 };
    ca.e[9]  = { dlin, wdlin, H_ * H_, 0 };
    ca.e[10] = { olin, wolin, H_ * H_, 0 };
    k_cvt_all<<<dim3(256, 11), 256, 0, stream>>>(ca);

    // 3. encoder convs (fused 3 branches, k=5 first) -> bufB
    {
        G3P p{}; p.A = Xh; p.W0 = wte1; p.W1 = wte3; p.W2 = wte5;
        p.lda = H_; p.outB = bufB; p.ldoB = H_; p.nMtiles = MTOK / 128;
        g3<true><<<3 * (MTOK / 128), 512, 0, stream>>>(p);
    }
    // 4. LN(conv + rep) -> bufC
    k_ln<<<MTOK, 192, 0, stream>>>(bufB, rep, lng, lnb, bufC);
    // 5. h2 = tanh(h_ln @ enc_lin^T) -> bufD
    {
        G3P p{}; p.A = bufC; p.W0 = welin; p.Ktot = H_; p.lda = H_;
        p.outB = bufD; p.ldoB = H_; p.act = 1;
        g3<false><<<dim3(MTOK / 128, H_ / 256), 512, 0, stream>>>(p);
    }
    // 6. location = h2 @ enc_tr^T -> out_loc (f32) + bufL (bf16)
    {
        GemmP p{}; p.A = bufD; p.lda = H_; p.Wt = wetr; p.Ktot = H_;
        p.outF = out_loc; p.ldoF = K_; p.outB = bufL; p.ldoB = K_;
        gemm_lds<64, 128><<<dim3(MTOK / 64, 1), 256, 0, stream>>>(p);
    }
    // 7. normed -> bufN
    k_normed<<<MTOK / 4, 256, 0, stream>>>(out_loc, bufN);
    // 8. d0 = location @ dec_tr^T -> Xh interior (halo rows stay zero)
    {
        GemmP p{}; p.A = bufL; p.lda = K_; p.Wt = wdtr; p.Ktot = K_;
        p.outB = Xh; p.ldoB = H_; p.outB_halo = 1;
        gemm_lds<128, 128><<<dim3(MTOK / 128, H_ / 128), 256, 0, stream>>>(p);
    }
    // 9. decoder convs -> bufB
    {
        G3P p{}; p.A = Xh; p.W0 = wtd1; p.W1 = wtd3; p.W2 = wtd5;
        p.lda = H_; p.outB = bufB; p.ldoB = H_; p.nMtiles = MTOK / 128;
        g3<true><<<3 * (MTOK / 128), 512, 0, stream>>>(p);
    }
    // 10. d2 = tanh(d1 @ dec_lin^T) -> bufC
    {
        G3P p{}; p.A = bufB; p.W0 = wdlin; p.Ktot = H_; p.lda = H_;
        p.outB = bufC; p.ldoB = H_; p.act = 1;
        g3<false><<<dim3(MTOK / 128, H_ / 256), 512, 0, stream>>>(p);
    }
    // 11. decode_out = d2 @ out_lin^T -> out_dec (f32)
    {
        G3P p{}; p.A = bufC; p.W0 = wolin; p.Ktot = H_; p.lda = H_;
        p.outF = out_dec; p.ldoF = H_;
        g3<false><<<dim3(MTOK / 128, H_ / 256), 512, 0, stream>>>(p);
    }
    // 12. banded cosine sim + tags -> out_dis, out_tag
    k_simtags<<<dim3(S_ / 64, S_ / 64, B_), 256, 0, stream>>>(bufN, mask, Lp, out_dis, out_tag);
}